// Round 5
// baseline (203.329 us; speedup 1.0000x reference)
//
#include <hip/hip_runtime.h>
#include <hip/hip_bf16.h>

#define BB 2
#define NN 384
#define DIM 256
#define HID 128
#define ROWS (BB*NN)   // 768

typedef __attribute__((ext_vector_type(8))) short bf16x8;
typedef __attribute__((ext_vector_type(4))) float f32x4;

static __device__ __forceinline__ unsigned int f2bf(float f) {
    unsigned int u = __builtin_bit_cast(unsigned int, f);
    return (u + 0x7FFFu + ((u >> 16) & 1u)) >> 16;   // RNE bf16 bits in low 16
}

// ---- qkv = x @ qkv_w + qkv_b (f32) -> separate q,k,v [row][256] (coalesced); + w2 prep ----
__global__ __launch_bounds__(256) void qkv_gemm(const float* __restrict__ x,
        const float* __restrict__ w, const float* __restrict__ bias,
        float* __restrict__ q, float* __restrict__ k, float* __restrict__ v,
        const float* __restrict__ w2, unsigned short* __restrict__ w2t) {
    __shared__ float xs[4][DIM];
    const int r0 = blockIdx.x * 4;
    const int t = threadIdx.x;

    // fused w2 [128][256] f32 -> w2t [256][128] bf16 (first 128 blocks)
    if (blockIdx.x < 128) {
        int g = blockIdx.x * 256 + t;         // g = h*256 + c
        w2t[(g & 255) * HID + (g >> 8)] = (unsigned short)f2bf(w2[g]);
    }

    #pragma unroll
    for (int i = 0; i < 4; ++i) xs[i][t] = x[(r0 + i) * DIM + t];
    __syncthreads();
    float acc[4][3];
    #pragma unroll
    for (int r = 0; r < 4; ++r) { acc[r][0]=0.f; acc[r][1]=0.f; acc[r][2]=0.f; }
    for (int kk0 = 0; kk0 < DIM; kk0 += 4) {
        float4 xv[4];
        #pragma unroll
        for (int r = 0; r < 4; ++r) xv[r] = *(const float4*)&xs[r][kk0];
        #pragma unroll
        for (int kk = 0; kk < 4; ++kk) {
            float w0 = w[(kk0+kk)*768 + t];
            float w1v = w[(kk0+kk)*768 + t + 256];
            float w2v = w[(kk0+kk)*768 + t + 512];
            #pragma unroll
            for (int r = 0; r < 4; ++r) {
                float xr = kk==0?xv[r].x : kk==1?xv[r].y : kk==2?xv[r].z : xv[r].w;
                acc[r][0] += xr*w0; acc[r][1] += xr*w1v; acc[r][2] += xr*w2v;
            }
        }
    }
    const float bq = bias[t], bk = bias[t+256], bv = bias[t+512];
    #pragma unroll
    for (int r = 0; r < 4; ++r) {
        q[(r0+r)*DIM + t] = acc[r][0] + bq;
        k[(r0+r)*DIM + t] = acc[r][1] + bk;
        v[(r0+r)*DIM + t] = acc[r][2] + bv;
    }
}

// ---------------- fused rel-pos MLP + per-channel fixed-max softmax ----------------
// 512 threads = 8 waves; wave wv owns channels [wv*32, wv*32+32)
__global__ __launch_bounds__(512, 6) void attn_main(
        const float* __restrict__ q,            // [ROWS][DIM]
        const float* __restrict__ k,            // [ROWS][DIM]
        const float* __restrict__ v,            // [ROWS][DIM]
        const float* __restrict__ pos,          // [ROWS][3]
        const unsigned char* __restrict__ mask, // [ROWS] (bool)
        const float* __restrict__ w1,           // [HID]
        const float* __restrict__ b1,           // [HID]
        const unsigned short* __restrict__ w2t, // [256][128] bf16, c-major
        const float* __restrict__ b2,           // [DIM]
        float* __restrict__ out_pre)            // [ROWS][DIM]
{
    __shared__ unsigned short hl[32][HID];  // swizzled 16B units: u' = u ^ ((j&7)<<1)
    __shared__ float w1s[HID], b1s[HID];
    __shared__ float dl[2][32];             // double-buffered per-j distance

    const int tid = threadIdx.x;
    const int row = blockIdx.x;             // b*N + i
    const int b = row / NN;
    const int l = tid & 63;
    const int wv = tid >> 6;                // 0..7
    const int lc = l & 15, lr = l >> 4;
    const int c0 = wv * 32;

    if (tid < HID) { w1s[tid] = w1[tid]; b1s[tid] = b1[tid]; }

    const float pix = pos[row*3+0], piy = pos[row*3+1], piz = pos[row*3+2];

    // prologue: distances for tile 0
    if (tid < 32) {
        int jg = b*NN + tid;
        float dx = pix - pos[jg*3+0], dy = piy - pos[jg*3+1], dz = piz - pos[jg*3+2];
        float sq = dx*dx + dy*dy + dz*dz;
        dl[0][tid] = sq > 0.f ? sqrtf(sq) : 0.f;
    }

    // B fragments (w2) from global, pinned in VGPRs (prevent remat-per-use)
    bf16x8 Bc[2][4];
    #pragma unroll
    for (int ct = 0; ct < 2; ++ct) {
        int c = c0 + ct * 16 + lc;
        #pragma unroll
        for (int kk = 0; kk < 4; ++kk) {
            Bc[ct][kk] = *(const bf16x8*)(w2t + c * HID + (kk * 4 + lr) * 8);
            asm volatile("" : "+v"(Bc[ct][kk]));
        }
    }

    float kq[2], b2v[2], b2v20[2];
    #pragma unroll
    for (int ct = 0; ct < 2; ++ct) {
        int c = c0 + ct * 16 + lc;
        kq[ct] = k[row * DIM + c];
        b2v[ct] = b2[c];
        b2v20[ct] = b2v[ct] - 20.f;   // fixed softmax max m=20 folded into bias
    }
    const bool mi = mask[row] != 0;

    float s[2] = {0.f, 0.f}, o[2] = {0.f, 0.f};

    const int jl_ = tid >> 4;               // stage: j index 0..31
    const int u_  = tid & 15;               // stage: k-group of 8
    const int up_ = u_ ^ ((jl_ & 7) << 1);

    for (int t = 0; t < 12; ++t) {
        const int jb = t * 32;
        __syncthreads();   // hl consumed by previous compute; dl[t&1] ready
        // stage h tile: h[j][k] = relu(d_ij * w1[k] + b1[k]) as bf16 (1 item/thread)
        {
            float d = dl[t & 1][jl_];
            if (tid < 32 && jb + 32 < NN) {       // precompute next tile's d
                int jg = b*NN + jb + 32 + tid;
                float dx = pix - pos[jg*3+0], dy = piy - pos[jg*3+1], dz = piz - pos[jg*3+2];
                float sq = dx*dx + dy*dy + dz*dz;
                dl[(t+1) & 1][tid] = sq > 0.f ? sqrtf(sq) : 0.f;
            }
            float4 wa = *(const float4*)&w1s[u_*8];
            float4 wb = *(const float4*)&w1s[u_*8+4];
            float4 ba = *(const float4*)&b1s[u_*8];
            float4 bb = *(const float4*)&b1s[u_*8+4];
            float h0 = fmaxf(fmaf(d, wa.x, ba.x), 0.f), h1 = fmaxf(fmaf(d, wa.y, ba.y), 0.f);
            float h2 = fmaxf(fmaf(d, wa.z, ba.z), 0.f), h3 = fmaxf(fmaf(d, wa.w, ba.w), 0.f);
            float h4 = fmaxf(fmaf(d, wb.x, bb.x), 0.f), h5 = fmaxf(fmaf(d, wb.y, bb.y), 0.f);
            float h6 = fmaxf(fmaf(d, wb.z, bb.z), 0.f), h7 = fmaxf(fmaf(d, wb.w, bb.w), 0.f);
            uint4 pkt;
            pkt.x = f2bf(h0) | (f2bf(h1) << 16);
            pkt.y = f2bf(h2) | (f2bf(h3) << 16);
            pkt.z = f2bf(h4) | (f2bf(h5) << 16);
            pkt.w = f2bf(h6) | (f2bf(h7) << 16);
            *(uint4*)&hl[jl_][up_ * 8] = pkt;
        }
        __syncthreads();

        #pragma unroll
        for (int jt = 0; jt < 2; ++jt) {
            bf16x8 Af[4];
            #pragma unroll
            for (int kk = 0; kk < 4; ++kk) {
                int jl = jt * 16 + lc;
                int up = (kk * 4 + lr) ^ ((jl & 7) << 1);
                Af[kk] = *(const bf16x8*)&hl[jl][up * 8];
            }
            const int jg0 = b * NN + jb + jt * 16 + (lr << 2);
            float qr[2][4], vr[2][4];
            f32x4 acc[2];
            #pragma unroll
            for (int ct = 0; ct < 2; ++ct) {
                const int c = c0 + ct * 16 + lc;
                const float* qp = q + jg0 * DIM + c;
                const float* vp = v + jg0 * DIM + c;
                #pragma unroll
                for (int r = 0; r < 4; ++r) { qr[ct][r] = qp[r * DIM]; vr[ct][r] = vp[r * DIM]; }
                acc[ct] = (f32x4){0.f, 0.f, 0.f, 0.f};
                #pragma unroll
                for (int kk = 0; kk < 4; ++kk)
                    acc[ct] = __builtin_amdgcn_mfma_f32_16x16x32_bf16(Af[kk], Bc[ct][kk], acc[ct], 0, 0, 0);
            }
            #pragma unroll
            for (int ct = 0; ct < 2; ++ct) {
                #pragma unroll
                for (int r = 0; r < 4; ++r) {
                    float rp  = acc[ct][r] + b2v[ct];                       // rel_pos (SCALE=1)
                    float lgt = fmaf(kq[ct], qr[ct][r], acc[ct][r] + b2v20[ct]);
                    float p = __expf(lgt);                                  // exp(logit - 20)
                    if (mi && mask[jg0 + r]) p = 0.f;
                    s[ct] += p;
                    o[ct] = fmaf(p, vr[ct][r] + rp, o[ct]);
                }
            }
        }
    }

    // merge (s,o) across the 4 j-lane-groups (plain sums: fixed max), write 32 c/wave
    #pragma unroll
    for (int ct = 0; ct < 2; ++ct) {
        float sv = s[ct], ov = o[ct];
        sv += __shfl_xor(sv, 16, 64); ov += __shfl_xor(ov, 16, 64);
        sv += __shfl_xor(sv, 32, 64); ov += __shfl_xor(ov, 32, 64);
        if (l < 16) out_pre[row * DIM + c0 + ct * 16 + l] = ov / sv;
    }
}

// ---------------- out = out_pre @ out_w + out_b (f32) ----------------
__global__ __launch_bounds__(256) void out_gemm(const float* __restrict__ a,
        const float* __restrict__ w, const float* __restrict__ bias,
        float* __restrict__ out) {
    __shared__ float as[4][DIM];
    const int r0 = blockIdx.x * 4;
    const int t = threadIdx.x;
    #pragma unroll
    for (int i = 0; i < 4; ++i) as[i][t] = a[(r0 + i) * DIM + t];
    __syncthreads();
    float acc[4] = {0.f, 0.f, 0.f, 0.f};
    for (int kk0 = 0; kk0 < DIM; kk0 += 4) {
        float4 xv[4];
        #pragma unroll
        for (int r = 0; r < 4; ++r) xv[r] = *(const float4*)&as[r][kk0];
        #pragma unroll
        for (int kk = 0; kk < 4; ++kk) {
            float wv = w[(kk0+kk)*DIM + t];
            #pragma unroll
            for (int r = 0; r < 4; ++r) {
                float xr = kk==0?xv[r].x : kk==1?xv[r].y : kk==2?xv[r].z : xv[r].w;
                acc[r] += xr * wv;
            }
        }
    }
    #pragma unroll
    for (int r = 0; r < 4; ++r) out[(r0+r)*DIM + t] = acc[r] + bias[t];
}

extern "C" void kernel_launch(void* const* d_in, const int* in_sizes, int n_in,
                              void* d_out, int out_size, void* d_ws, size_t ws_size,
                              hipStream_t stream) {
    const float* x      = (const float*)d_in[0];
    const float* pos    = (const float*)d_in[1];
    const unsigned char* mask = (const unsigned char*)d_in[2];
    const float* qkv_w  = (const float*)d_in[3];
    const float* qkv_b  = (const float*)d_in[4];
    const float* pm_w1  = (const float*)d_in[5];
    const float* pm_b1  = (const float*)d_in[6];
    const float* pm_w2  = (const float*)d_in[7];
    const float* pm_b2  = (const float*)d_in[8];
    const float* out_w  = (const float*)d_in[9];
    const float* out_b  = (const float*)d_in[10];
    float* out = (float*)d_out;

    char* ws = (char*)d_ws;
    float* qb           = (float*)(ws);                 // 768*256*4 = 786,432 B
    float* kb           = (float*)(ws +  786432);       // 786,432 B
    float* vb           = (float*)(ws + 1572864);       // 786,432 B
    float* out_pre      = (float*)(ws + 2359296);       // 786,432 B
    unsigned short* w2t = (unsigned short*)(ws + 3145728); // 65,536 B

    hipLaunchKernelGGL(qkv_gemm, dim3(ROWS/4), dim3(256), 0, stream,
                       x, qkv_w, qkv_b, qb, kb, vb, pm_w2, w2t);
    hipLaunchKernelGGL(attn_main, dim3(ROWS), dim3(512), 0, stream,
                       qb, kb, vb, pos, mask, pm_w1, pm_b1, w2t, pm_b2, out_pre);
    hipLaunchKernelGGL(out_gemm, dim3(ROWS/4), dim3(256), 0, stream, out_pre, out_w, out_b, out);
}

// Round 6
// 85.645 us; speedup vs baseline: 2.3741x; 2.3741x over previous
//
#include <hip/hip_runtime.h>
#include <hip/hip_bf16.h>

#define BB 2
#define NN 384
#define DIM 256
#define HID 128
#define ROWS (BB*NN)   // 768
#define LOG2E 1.4426950408889634f

typedef __attribute__((ext_vector_type(8))) short bf16x8;
typedef __attribute__((ext_vector_type(4))) float f32x4;

static __device__ __forceinline__ unsigned int f2bf(float f) {
    unsigned int u = __builtin_bit_cast(unsigned int, f);
    return (u + 0x7FFFu + ((u >> 16) & 1u)) >> 16;   // RNE bf16 bits in low 16
}

// ---- qkv = x @ qkv_w + qkv_b (f32) -> q,k,v [row][256] coalesced; 6 rows/block; + w2 prep ----
__global__ __launch_bounds__(256) void qkv_gemm(const float* __restrict__ x,
        const float* __restrict__ w, const float* __restrict__ bias,
        float* __restrict__ q, float* __restrict__ k, float* __restrict__ v,
        const float* __restrict__ w2, unsigned short* __restrict__ w2t) {
    __shared__ float xs[6][DIM];
    const int r0 = blockIdx.x * 6;            // 128 blocks x 6 rows = 768
    const int t = threadIdx.x;

    // fused w2 [128][256] f32 -> w2t [256][128] bf16 (exactly 128 blocks)
    {
        int g = blockIdx.x * 256 + t;         // g = h*256 + c
        w2t[(g & 255) * HID + (g >> 8)] = (unsigned short)f2bf(w2[g]);
    }

    #pragma unroll
    for (int i = 0; i < 6; ++i) xs[i][t] = x[(r0 + i) * DIM + t];
    __syncthreads();
    float acc[6][3];
    #pragma unroll
    for (int r = 0; r < 6; ++r) { acc[r][0]=0.f; acc[r][1]=0.f; acc[r][2]=0.f; }
    for (int kk0 = 0; kk0 < DIM; kk0 += 4) {
        float4 xv[6];
        #pragma unroll
        for (int r = 0; r < 6; ++r) xv[r] = *(const float4*)&xs[r][kk0];
        #pragma unroll
        for (int kk = 0; kk < 4; ++kk) {
            float w0  = w[(kk0+kk)*768 + t];
            float w1v = w[(kk0+kk)*768 + t + 256];
            float w2v = w[(kk0+kk)*768 + t + 512];
            #pragma unroll
            for (int r = 0; r < 6; ++r) {
                float xr = kk==0?xv[r].x : kk==1?xv[r].y : kk==2?xv[r].z : xv[r].w;
                acc[r][0] += xr*w0; acc[r][1] += xr*w1v; acc[r][2] += xr*w2v;
            }
        }
    }
    const float bq = bias[t], bk = bias[t+256], bv = bias[t+512];
    #pragma unroll
    for (int r = 0; r < 6; ++r) {
        q[(r0+r)*DIM + t] = acc[r][0] + bq;
        k[(r0+r)*DIM + t] = acc[r][1] + bk;
        v[(r0+r)*DIM + t] = acc[r][2] + bv;
    }
}

// ---------------- fused rel-pos MLP + per-channel fixed-max softmax ----------------
// 512 threads = 8 waves; wave wv owns channels [wv*32, wv*32+32).
// LDS plan (64 KB total, aliased): phase 0 = w2 bf16 stage [256][128] (full 64 KB);
// after Bc extraction the same bytes hold hl[32][128] (8 KB) + dl/w1s/b1s (1.25 KB).
__global__ __launch_bounds__(512, 4) void attn_main(
        const float* __restrict__ q,            // [ROWS][DIM]
        const float* __restrict__ k,            // [ROWS][DIM]
        const float* __restrict__ v,            // [ROWS][DIM]
        const float* __restrict__ pos,          // [ROWS][3]
        const unsigned char* __restrict__ mask, // [ROWS] (bool)
        const float* __restrict__ w1,           // [HID]
        const float* __restrict__ b1,           // [HID]
        const unsigned short* __restrict__ w2t, // [256][128] bf16, c-major
        const float* __restrict__ b2,           // [DIM]
        float* __restrict__ out_pre)            // [ROWS][DIM]
{
    __shared__ char smem[65536];
    unsigned short (*w2l)[HID] = (unsigned short (*)[HID])smem;  // phase 0
    unsigned short (*hl)[HID]  = (unsigned short (*)[HID])smem;  // loop phase (aliases w2l)
    float* dl  = (float*)(smem + 8192);    // [2][32]
    float* w1s = (float*)(smem + 8448);    // [128]
    float* b1s = (float*)(smem + 8960);    // [128]

    const int tid = threadIdx.x;
    const int row = blockIdx.x;             // b*N + i
    const int b = row / NN;
    const int l = tid & 63;
    const int wv = tid >> 6;                // 0..7
    const int lc = l & 15, lr = l >> 4;
    const int c0 = wv * 32;

    // ---- phase 0: stage w2 bf16 into LDS, swizzled 16B units: u' = u ^ ((c&3)<<2) ----
    #pragma unroll
    for (int it = 0; it < 8; ++it) {
        int f = tid + (it << 9);            // chunk id 0..4095: c = f>>4, u = f&15
        int c = f >> 4, u = f & 15;
        int up = u ^ ((c & 3) << 2);
        *(uint4*)&w2l[c][up * 8] = *(const uint4*)(w2t + c * HID + u * 8);
    }
    __syncthreads();

    // ---- extract Bc fragments; LDS source will be clobbered => guaranteed VGPR-resident ----
    bf16x8 Bc[2][4];
    #pragma unroll
    for (int ct = 0; ct < 2; ++ct) {
        int c = c0 + ct * 16 + lc;
        #pragma unroll
        for (int kk = 0; kk < 4; ++kk) {
            int up = (kk * 4 + lr) ^ ((c & 3) << 2);
            Bc[ct][kk] = *(const bf16x8*)&w2l[c][up * 8];
        }
    }
    __syncthreads();   // all waves done reading w2l before anyone overwrites it

    const float pix = pos[row*3+0], piy = pos[row*3+1], piz = pos[row*3+2];
    if (tid < HID) { w1s[tid] = w1[tid]; b1s[tid] = b1[tid]; }
    if (tid < 32) {     // distances for tile 0
        int jg = b*NN + tid;
        float dx = pix - pos[jg*3+0], dy = piy - pos[jg*3+1], dz = piz - pos[jg*3+2];
        float sq = dx*dx + dy*dy + dz*dz;
        dl[tid] = sq > 0.f ? sqrtf(sq) : 0.f;
    }

    float kq2[2], b2v[2], b2c[2];
    #pragma unroll
    for (int ct = 0; ct < 2; ++ct) {
        int c = c0 + ct * 16 + lc;
        float kq = k[row * DIM + c];
        kq2[ct] = kq * LOG2E;
        b2v[ct] = b2[c];
        b2c[ct] = (b2v[ct] - 20.f) * LOG2E;   // fixed softmax max m=20, folded, log2-domain
    }
    const bool mi = mask[row] != 0;

    float s[2] = {0.f, 0.f}, o[2] = {0.f, 0.f};

    const int jl_ = tid >> 4;               // stage: j index 0..31
    const int u_  = tid & 15;               // stage: k-group of 8
    const int up_ = u_ ^ ((jl_ & 7) << 1);

    for (int t = 0; t < 12; ++t) {
        const int jb = t * 32;
        __syncthreads();   // t=0: w1s/dl ready; t>0: hl consumed by previous compute
        // stage h tile: h[j][k] = relu(d_ij * w1[k] + b1[k]) as bf16 (1 item/thread)
        {
            float d = dl[(t & 1) * 32 + jl_];
            if (tid < 32 && jb + 32 < NN) {       // precompute next tile's d
                int jg = b*NN + jb + 32 + tid;
                float dx = pix - pos[jg*3+0], dy = piy - pos[jg*3+1], dz = piz - pos[jg*3+2];
                float sq = dx*dx + dy*dy + dz*dz;
                dl[((t+1) & 1) * 32 + tid] = sq > 0.f ? sqrtf(sq) : 0.f;
            }
            float4 wa = *(const float4*)&w1s[u_*8];
            float4 wb = *(const float4*)&w1s[u_*8+4];
            float4 ba = *(const float4*)&b1s[u_*8];
            float4 bb = *(const float4*)&b1s[u_*8+4];
            float h0 = fmaxf(fmaf(d, wa.x, ba.x), 0.f), h1 = fmaxf(fmaf(d, wa.y, ba.y), 0.f);
            float h2 = fmaxf(fmaf(d, wa.z, ba.z), 0.f), h3 = fmaxf(fmaf(d, wa.w, ba.w), 0.f);
            float h4 = fmaxf(fmaf(d, wb.x, bb.x), 0.f), h5 = fmaxf(fmaf(d, wb.y, bb.y), 0.f);
            float h6 = fmaxf(fmaf(d, wb.z, bb.z), 0.f), h7 = fmaxf(fmaf(d, wb.w, bb.w), 0.f);
            uint4 pkt;
            pkt.x = f2bf(h0) | (f2bf(h1) << 16);
            pkt.y = f2bf(h2) | (f2bf(h3) << 16);
            pkt.z = f2bf(h4) | (f2bf(h5) << 16);
            pkt.w = f2bf(h6) | (f2bf(h7) << 16);
            *(uint4*)&hl[jl_][up_ * 8] = pkt;
        }
        __syncthreads();

        #pragma unroll
        for (int jt = 0; jt < 2; ++jt) {
            bf16x8 Af[4];
            #pragma unroll
            for (int kk = 0; kk < 4; ++kk) {
                int jl = jt * 16 + lc;
                int up = (kk * 4 + lr) ^ ((jl & 7) << 1);
                Af[kk] = *(const bf16x8*)&hl[jl][up * 8];
            }
            const int jg0 = b * NN + jb + jt * 16 + (lr << 2);
            float qr[2][4], vr[2][4];
            f32x4 acc[2];
            #pragma unroll
            for (int ct = 0; ct < 2; ++ct) {
                const int c = c0 + ct * 16 + lc;
                const float* qp = q + jg0 * DIM + c;
                const float* vp = v + jg0 * DIM + c;
                #pragma unroll
                for (int r = 0; r < 4; ++r) { qr[ct][r] = qp[r * DIM]; vr[ct][r] = vp[r * DIM]; }
                acc[ct] = (f32x4){0.f, 0.f, 0.f, 0.f};
                #pragma unroll
                for (int kk = 0; kk < 4; ++kk)
                    acc[ct] = __builtin_amdgcn_mfma_f32_16x16x32_bf16(Af[kk], Bc[ct][kk], acc[ct], 0, 0, 0);
            }
            #pragma unroll
            for (int ct = 0; ct < 2; ++ct) {
                #pragma unroll
                for (int r = 0; r < 4; ++r) {
                    float rp   = acc[ct][r] + b2v[ct];                     // rel_pos (SCALE=1)
                    float t1   = fmaf(acc[ct][r], LOG2E, b2c[ct]);
                    float lgt2 = fmaf(kq2[ct], qr[ct][r], t1);             // (logit-20)*log2e
                    float p = exp2f(lgt2);
                    if (mi && mask[jg0 + r]) p = 0.f;
                    s[ct] += p;
                    o[ct] = fmaf(p, vr[ct][r] + rp, o[ct]);
                }
            }
        }
    }

    // merge (s,o) across the 4 j-lane-groups (plain sums: fixed max), write 32 c/wave
    #pragma unroll
    for (int ct = 0; ct < 2; ++ct) {
        float sv = s[ct], ov = o[ct];
        sv += __shfl_xor(sv, 16, 64); ov += __shfl_xor(ov, 16, 64);
        sv += __shfl_xor(sv, 32, 64); ov += __shfl_xor(ov, 32, 64);
        if (l < 16) out_pre[row * DIM + c0 + ct * 16 + l] = ov / sv;
    }
}

// ---------------- out = out_pre @ out_w + out_b (f32), 6 rows/block ----------------
__global__ __launch_bounds__(256) void out_gemm(const float* __restrict__ a,
        const float* __restrict__ w, const float* __restrict__ bias,
        float* __restrict__ out) {
    __shared__ float as[6][DIM];
    const int r0 = blockIdx.x * 6;
    const int t = threadIdx.x;
    #pragma unroll
    for (int i = 0; i < 6; ++i) as[i][t] = a[(r0 + i) * DIM + t];
    __syncthreads();
    float acc[6] = {0.f, 0.f, 0.f, 0.f, 0.f, 0.f};
    for (int kk0 = 0; kk0 < DIM; kk0 += 4) {
        float4 xv[6];
        #pragma unroll
        for (int r = 0; r < 6; ++r) xv[r] = *(const float4*)&as[r][kk0];
        #pragma unroll
        for (int kk = 0; kk < 4; ++kk) {
            float wv = w[(kk0+kk)*DIM + t];
            #pragma unroll
            for (int r = 0; r < 6; ++r) {
                float xr = kk==0?xv[r].x : kk==1?xv[r].y : kk==2?xv[r].z : xv[r].w;
                acc[r] += xr * wv;
            }
        }
    }
    #pragma unroll
    for (int r = 0; r < 6; ++r) out[(r0+r)*DIM + t] = acc[r] + bias[t];
}

extern "C" void kernel_launch(void* const* d_in, const int* in_sizes, int n_in,
                              void* d_out, int out_size, void* d_ws, size_t ws_size,
                              hipStream_t stream) {
    const float* x      = (const float*)d_in[0];
    const float* pos    = (const float*)d_in[1];
    const unsigned char* mask = (const unsigned char*)d_in[2];
    const float* qkv_w  = (const float*)d_in[3];
    const float* qkv_b  = (const float*)d_in[4];
    const float* pm_w1  = (const float*)d_in[5];
    const float* pm_b1  = (const float*)d_in[6];
    const float* pm_w2  = (const float*)d_in[7];
    const float* pm_b2  = (const float*)d_in[8];
    const float* out_w  = (const float*)d_in[9];
    const float* out_b  = (const float*)d_in[10];
    float* out = (float*)d_out;

    char* ws = (char*)d_ws;
    float* qb           = (float*)(ws);                 // 768*256*4 = 786,432 B
    float* kb           = (float*)(ws +  786432);       // 786,432 B
    float* vb           = (float*)(ws + 1572864);       // 786,432 B
    float* out_pre      = (float*)(ws + 2359296);       // 786,432 B
    unsigned short* w2t = (unsigned short*)(ws + 3145728); // 65,536 B

    hipLaunchKernelGGL(qkv_gemm, dim3(ROWS/6), dim3(256), 0, stream,
                       x, qkv_w, qkv_b, qb, kb, vb, pm_w2, w2t);
    hipLaunchKernelGGL(attn_main, dim3(ROWS), dim3(512), 0, stream,
                       qb, kb, vb, pos, mask, pm_w1, pm_b1, w2t, pm_b2, out_pre);
    hipLaunchKernelGGL(out_gemm, dim3(ROWS/6), dim3(256), 0, stream, out_pre, out_w, out_b, out);
}